// Round 1
// baseline (2913.024 us; speedup 1.0000x reference)
//
#include <hip/hip_runtime.h>

// Exact-order float32 arithmetic: numpy/jax evaluate left-to-right with no
// FMA contraction. hipcc defaults to -ffp-contract=fast, which would fuse
// 0.04*v*v + ... and change rounding -> possible spike-time shift -> ~85
// voltage absmax error. Disable contraction for this file.
#pragma clang fp contract(off)

// One Izhikevich update in the reference's exact evaluation order:
//   v1 = v + 0.25f*((((0.04f*v)*v + 5.0f*v) + 140.0f - u) + I)
//   u1 = u + ka*(b*v - u)            (ka = float(0.25 * a), folded in f64)
//   z  = (v1 >= 30)
//   v  = z ? c : v1
//   u  = u1 + z*d   (z in {0,1} so this is exactly u1 or u1+d)
__device__ __forceinline__ float izh_step(float& v, float& u, float I,
                                          float ka, float b, float c, float d) {
    float t1 = 0.04f * v;
    float t2 = t1 * v;
    float t3 = 5.0f * v;
    float t4 = t2 + t3;
    float t5 = t4 + 140.0f;
    float t6 = t5 - u;
    float t7 = t6 + I;
    float dv = 0.25f * t7;     // TAU*DT = 250.0*0.001 = 0.25 exactly
    float v1 = v + dv;
    float bv = b * v;
    float bvu = bv - u;
    float du = ka * bvu;
    float u1 = u + du;
    bool fire = (v1 >= 30.0f);
    float z = fire ? 1.0f : 0.0f;
    v = fire ? c : v1;
    u = fire ? (u1 + d) : u1;  // z*d is exactly d or 0; u1+0.0f == u1
    return z;
}

__global__ __launch_bounds__(256) void net_sim(const float* __restrict__ mat,
                                               const float* __restrict__ w,
                                               float* __restrict__ out,
                                               int T) {
    __shared__ double red[256];
    const int tid = threadIdx.x;

    // ---- z_plus = sum(input_mat * w0), f32 products accumulated in f64 ----
    const float w0 = w[0];
    double s = 0.0;
    for (int i = tid; i < 127 * 127; i += 256) {
        float p = mat[i] * w0;   // elementwise product rounded to f32 (as ref)
        s += (double)p;
    }
    red[tid] = s;
    __syncthreads();
    #pragma unroll
    for (int off = 128; off > 0; off >>= 1) {
        if (tid < off) red[tid] += red[tid + off];
        __syncthreads();
    }
    if (tid != 0) return;

    // ---- serial time loop on thread 0 ----
    const float z_plus = (float)red[0];

    const float w1 = w[1], w2 = w[2], w3 = w[3], w4 = w[4], w5 = w[5],
                w6 = w[6], w7 = w[7], w8 = w[8], w9 = w[9], w10 = w[10],
                w11 = w[11];
    const float zp_w1 = z_plus * w1;   // constant across steps (same rounding)
    const float zp_w4 = z_plus * w4;

    // ka = float(0.25 * a): Python computes TAU*DT*a in f64, casts to f32 on use
    const float kaL = (float)(0.25 * 0.1);    // LLBN a=0.1  -> 0.025f
    const float kaP = (float)(0.25 * 0.02);   // others a=0.02 -> 0.005f

    float temp = 0.0f;
    float z2p = 0.0f, v2 = -60.0f, u2 = 4.5f;      // LLBN
    float v3 = -64.0f, u3 = -16.0f;                 // EBN
    float v4 = -64.0f, u4 = -16.0f;                 // IFN
    float z5p = 0.0f, v5 = -70.0f, u5 = -14.0f;     // TN
    float v6 = -64.0f, u6 = -16.0f;                 // MN

    float* out_sp = out;           // spikes [5][T]
    float* out_v  = out + 5 * T;   // volts  [5][T]

    for (int t = 0; t < T; ++t) {
        // LLBN: I = w2*(z_plus*w1 - temp) + w3*z2_prev
        float I2 = w2 * (zp_w1 - temp) + w3 * z2p;
        float z2 = izh_step(v2, u2, I2, kaL, -0.075f, -55.0f, 6.0f);
        // EBN: I = z_plus*w4 + z2*w5
        float I3 = zp_w4 + z2 * w5;
        float z3 = izh_step(v3, u3, I3, kaP, 0.25f, -55.0f, 0.05f);
        // IFN: I = z3*w6 ; feedback temp = z4*w7 (one-step delay)
        float I4 = z3 * w6;
        float z4 = izh_step(v4, u4, I4, kaP, 0.25f, -65.0f, 6.0f);
        temp = z4 * w7;
        // TN: I = w9*(z3*w8) + w10*z5_prev
        float I5 = w9 * (z3 * w8) + w10 * z5p;
        float z5 = izh_step(v5, u5, I5, kaP, 0.2f, -65.0f, 6.0f);
        // MN: I = z5*w11
        float I6 = z5 * w11;
        float z6 = izh_step(v6, u6, I6, kaP, 0.25f, -65.0f, 6.0f);

        z2p = z2;
        z5p = z5;

        out_sp[t]          = z2;
        out_sp[T + t]      = z3;
        out_sp[2 * T + t]  = z4;
        out_sp[3 * T + t]  = z5;
        out_sp[4 * T + t]  = z6;
        out_v[t]           = v2;
        out_v[T + t]       = v3;
        out_v[2 * T + t]   = v4;
        out_v[3 * T + t]   = v5;
        out_v[4 * T + t]   = v6;
    }
}

extern "C" void kernel_launch(void* const* d_in, const int* in_sizes, int n_in,
                              void* d_out, int out_size, void* d_ws, size_t ws_size,
                              hipStream_t stream) {
    const float* mat = (const float*)d_in[0];
    const float* w   = (const float*)d_in[1];
    // out_size = 2 outputs * 5 neurons * T  -> T = out_size/10
    int T = out_size / 10;
    net_sim<<<1, 256, 0, stream>>>(mat, w, (float*)d_out, T);
}

// Round 2
// 1829.701 us; speedup vs baseline: 1.5921x; 1.5921x over previous
//
#include <hip/hip_runtime.h>

// Exact-order float32 arithmetic: numpy/jax evaluate left-to-right with no
// FMA contraction. hipcc defaults to -ffp-contract=fast, which would fuse
// 0.04*v*v + ... and change rounding -> possible spike-time shift -> ~85
// voltage absmax error. Disable contraction for this file.
#pragma clang fp contract(off)

// One Izhikevich update in the reference's exact evaluation order.
// I is supplied pre-selected from a constant set (exactness argued below).
__device__ __forceinline__ void izh_step(float& v, float& u, float I,
                                         float ka, float b, float c, float d,
                                         bool& fire, float& z) {
    float t1 = 0.04f * v;
    float t2 = t1 * v;
    float t3 = 5.0f * v;
    float t4 = t2 + t3;
    float t5 = t4 + 140.0f;
    float t6 = t5 - u;
    float t7 = t6 + I;
    float dv = 0.25f * t7;     // TAU*DT = 250*0.001 = 0.25 exactly
    float v1 = v + dv;
    float bv = b * v;
    float bvu = bv - u;
    float du = ka * bvu;
    float u1 = u + du;
    fire = (v1 >= 30.0f);
    z = fire ? 1.0f : 0.0f;
    v = fire ? c : v1;
    u = fire ? (u1 + d) : u1;  // z*d is exactly d or +0.0f; u1+0.0f == u1 (value-equal)
}

__global__ __launch_bounds__(256) void net_sim(const float* __restrict__ mat,
                                               const float* __restrict__ w,
                                               float* __restrict__ out,
                                               int T) {
    __shared__ double red[256];
    const int tid = threadIdx.x;

    // ---- z_plus = sum(input_mat * w0), f32 products accumulated in f64 ----
    const float w0 = w[0];
    double s = 0.0;
    for (int i = tid; i < 127 * 127; i += 256) {
        float p = mat[i] * w0;   // elementwise product rounded to f32 (as ref)
        s += (double)p;
    }
    red[tid] = s;
    __syncthreads();
    #pragma unroll
    for (int off = 128; off > 0; off >>= 1) {
        if (tid < off) red[tid] += red[tid + off];
        __syncthreads();
    }
    if (tid != 0) return;

    // ---- serial time loop on thread 0 ----
    const float z_plus = (float)red[0];

    const float w2 = w[2], w3 = w[3], w5 = w[5],
                w6 = w[6], w7 = w[7], w8 = w[8], w9 = w[9], w10 = w[10],
                w11 = w[11];
    const float zp_w1 = z_plus * w[1];   // constant across steps (same rounding)
    const float zp_w4 = z_plus * w[4];

    // All input currents take values in small constant sets since spikes are
    // {0,1}. Each constant below reproduces the reference's per-step
    // expression bit-exactly for that (spike-combo): z*w is exactly +0.0f or
    // w, and x + (+0.0f) == x for the nonzero/positive x involved.
    // I2 = w2*(zp_w1 - temp) + w3*z2p,  temp in {0, w7}, z2p in {0,1}
    const float I2_00 = w2 * (zp_w1 - 0.0f) + w3 * 0.0f;  // z2p=0, z4p=0
    const float I2_10 = w2 * (zp_w1 - 0.0f) + w3 * 1.0f;  // z2p=1, z4p=0
    const float I2_01 = w2 * (zp_w1 - w7)   + w3 * 0.0f;  // z2p=0, z4p=1
    const float I2_11 = w2 * (zp_w1 - w7)   + w3 * 1.0f;  // z2p=1, z4p=1
    // I3 = zp_w4 + z2*w5
    const float I3_0 = zp_w4 + 0.0f * w5;
    const float I3_1 = zp_w4 + 1.0f * w5;
    // I4 = z3*w6
    const float I4_0 = 0.0f * w6;
    const float I4_1 = 1.0f * w6;
    // I5 = w9*(z3*w8) + w10*z5p
    const float I5_00 = w9 * (0.0f * w8) + w10 * 0.0f;
    const float I5_10 = w9 * (1.0f * w8) + w10 * 0.0f;  // z3=1, z5p=0
    const float I5_01 = w9 * (0.0f * w8) + w10 * 1.0f;  // z3=0, z5p=1
    const float I5_11 = w9 * (1.0f * w8) + w10 * 1.0f;
    // I6 = z5*w11
    const float I6_0 = 0.0f * w11;
    const float I6_1 = 1.0f * w11;

    // ka = float(0.25 * a): Python computes TAU*DT*a in f64, casts to f32 on use
    const float kaL = (float)(0.25 * 0.1);    // LLBN a=0.1  -> 0.025f
    const float kaP = (float)(0.25 * 0.02);   // others a=0.02 -> 0.005f

    bool f2p = false, f4p = false, f5p = false;   // prev-step fire flags
    float v2 = -60.0f, u2 = 4.5f;      // LLBN
    float v3 = -64.0f, u3 = -16.0f;    // EBN
    float v4 = -64.0f, u4 = -16.0f;    // IFN
    float v5 = -70.0f, u5 = -14.0f;    // TN
    float v6 = -64.0f, u6 = -16.0f;    // MN

    float* out_sp = out;           // spikes [5][T]
    float* out_v  = out + 5 * T;   // volts  [5][T]

    float zb2[4], zb3[4], zb4[4], zb5[4], zb6[4];
    float vb2[4], vb3[4], vb4[4], vb5[4], vb6[4];

    int t = 0;
    for (; t + 4 <= T; t += 4) {
        #pragma unroll
        for (int j = 0; j < 4; ++j) {
            // LLBN — select I2 from prev-step flags (off critical path)
            float I2 = f4p ? (f2p ? I2_11 : I2_01) : (f2p ? I2_10 : I2_00);
            bool f2; float z2;
            izh_step(v2, u2, I2, kaL, -0.075f, -55.0f, 6.0f, f2, z2);
            // EBN
            float I3 = f2 ? I3_1 : I3_0;
            bool f3; float z3;
            izh_step(v3, u3, I3, kaP, 0.25f, -55.0f, 0.05f, f3, z3);
            // IFN (feedback to LLBN next step via f4p)
            float I4 = f3 ? I4_1 : I4_0;
            bool f4; float z4;
            izh_step(v4, u4, I4, kaP, 0.25f, -65.0f, 6.0f, f4, z4);
            // TN
            float I5 = f3 ? (f5p ? I5_11 : I5_10) : (f5p ? I5_01 : I5_00);
            bool f5; float z5;
            izh_step(v5, u5, I5, kaP, 0.2f, -65.0f, 6.0f, f5, z5);
            // MN
            float I6 = f5 ? I6_1 : I6_0;
            bool f6; float z6;
            izh_step(v6, u6, I6, kaP, 0.25f, -65.0f, 6.0f, f6, z6);

            f2p = f2; f4p = f4; f5p = f5;
            zb2[j] = z2; zb3[j] = z3; zb4[j] = z4; zb5[j] = z5; zb6[j] = z6;
            vb2[j] = v2; vb3[j] = v3; vb4[j] = v4; vb5[j] = v5; vb6[j] = v6;
        }
        // vectorized stores: rows are T-long (T%4==0), 16B-aligned
        *(float4*)(out_sp + t)         = make_float4(zb2[0], zb2[1], zb2[2], zb2[3]);
        *(float4*)(out_sp + T + t)     = make_float4(zb3[0], zb3[1], zb3[2], zb3[3]);
        *(float4*)(out_sp + 2 * T + t) = make_float4(zb4[0], zb4[1], zb4[2], zb4[3]);
        *(float4*)(out_sp + 3 * T + t) = make_float4(zb5[0], zb5[1], zb5[2], zb5[3]);
        *(float4*)(out_sp + 4 * T + t) = make_float4(zb6[0], zb6[1], zb6[2], zb6[3]);
        *(float4*)(out_v + t)          = make_float4(vb2[0], vb2[1], vb2[2], vb2[3]);
        *(float4*)(out_v + T + t)      = make_float4(vb3[0], vb3[1], vb3[2], vb3[3]);
        *(float4*)(out_v + 2 * T + t)  = make_float4(vb4[0], vb4[1], vb4[2], vb4[3]);
        *(float4*)(out_v + 3 * T + t)  = make_float4(vb5[0], vb5[1], vb5[2], vb5[3]);
        *(float4*)(out_v + 4 * T + t)  = make_float4(vb6[0], vb6[1], vb6[2], vb6[3]);
    }
    // tail (T not divisible by 4)
    for (; t < T; ++t) {
        float I2 = f4p ? (f2p ? I2_11 : I2_01) : (f2p ? I2_10 : I2_00);
        bool f2; float z2;
        izh_step(v2, u2, I2, kaL, -0.075f, -55.0f, 6.0f, f2, z2);
        float I3 = f2 ? I3_1 : I3_0;
        bool f3; float z3;
        izh_step(v3, u3, I3, kaP, 0.25f, -55.0f, 0.05f, f3, z3);
        float I4 = f3 ? I4_1 : I4_0;
        bool f4; float z4;
        izh_step(v4, u4, I4, kaP, 0.25f, -65.0f, 6.0f, f4, z4);
        float I5 = f3 ? (f5p ? I5_11 : I5_10) : (f5p ? I5_01 : I5_00);
        bool f5; float z5;
        izh_step(v5, u5, I5, kaP, 0.2f, -65.0f, 6.0f, f5, z5);
        float I6 = f5 ? I6_1 : I6_0;
        bool f6; float z6;
        izh_step(v6, u6, I6, kaP, 0.25f, -65.0f, 6.0f, f6, z6);
        f2p = f2; f4p = f4; f5p = f5;
        out_sp[t] = z2; out_sp[T + t] = z3; out_sp[2 * T + t] = z4;
        out_sp[3 * T + t] = z5; out_sp[4 * T + t] = z6;
        out_v[t] = v2; out_v[T + t] = v3; out_v[2 * T + t] = v4;
        out_v[3 * T + t] = v5; out_v[4 * T + t] = v6;
    }
}

extern "C" void kernel_launch(void* const* d_in, const int* in_sizes, int n_in,
                              void* d_out, int out_size, void* d_ws, size_t ws_size,
                              hipStream_t stream) {
    const float* mat = (const float*)d_in[0];
    const float* w   = (const float*)d_in[1];
    // out_size = 2 outputs * 5 neurons * T  -> T = out_size/10
    int T = out_size / 10;
    net_sim<<<1, 256, 0, stream>>>(mat, w, (float*)d_out, T);
}

// Round 3
// 1751.592 us; speedup vs baseline: 1.6631x; 1.0446x over previous
//
#include <hip/hip_runtime.h>

// Exact-order float32 arithmetic: numpy/jax evaluate left-to-right with no
// FMA contraction. hipcc defaults to -ffp-contract=fast, which would change
// rounding -> possible spike-time shift -> large voltage absmax error.
#pragma clang fp contract(off)

// Lane-parallel speculative Izhikevich network.
// Lanes 0..13 of wave 0 each hold one speculative variant of one neuron:
//   lanes 0-3 : LLBN with I2 for (z2p,z4p) = (0,0),(1,0),(0,1),(1,1)
//   lanes 4-5 : EBN  with I3 for z2 = 0,1
//   lanes 6-7 : IFN  with I4 for z3 = 0,1
//   lanes 8-11: TN   with I5 for (z3,z5p) = (0,0),(1,0),(0,1),(1,1)
//   lanes 12-13: MN  with I6 for z5 = 0,1
// One izh instruction sequence per step updates ALL variants (wave64 SIMD).
// Spike resolution is scalar bit-logic on the __ballot mask; actual (v,u)
// is broadcast back to each group's lanes via ds_bpermute. Each lane's I is
// a loop-invariant constant identical to the validated R2 constant set, so
// the selected trajectory is bit-exact vs the reference.

__global__ __launch_bounds__(256) void net_sim(const float* __restrict__ mat,
                                               const float* __restrict__ w,
                                               float* __restrict__ out,
                                               int T) {
    __shared__ double red[256];
    const int tid = threadIdx.x;

    // ---- z_plus = sum(input_mat * w0), f32 products accumulated in f64 ----
    const float w0 = w[0];
    double s = 0.0;
    for (int i = tid; i < 127 * 127; i += 256) {
        float p = mat[i] * w0;   // elementwise product rounded to f32 (as ref)
        s += (double)p;
    }
    red[tid] = s;
    __syncthreads();
    #pragma unroll
    for (int off = 128; off > 0; off >>= 1) {
        if (tid < off) red[tid] += red[tid + off];
        __syncthreads();
    }
    if (tid >= 14) return;   // 14 lanes of wave 0 continue; no more barriers

    const float z_plus = (float)red[0];

    const float w2 = w[2], w3 = w[3], w5 = w[5], w6 = w[6], w7 = w[7],
                w8 = w[8], w9 = w[9], w10 = w[10], w11 = w[11];
    const float zp_w1 = z_plus * w[1];
    const float zp_w4 = z_plus * w[4];

    // Validated (R2, absmax 0.0) constant-I set. z*w is exactly +0.0f or w;
    // x + (+0.0f) == x for the values involved.
    const float I2_00 = w2 * (zp_w1 - 0.0f) + w3 * 0.0f;
    const float I2_10 = w2 * (zp_w1 - 0.0f) + w3 * 1.0f;
    const float I2_01 = w2 * (zp_w1 - w7)   + w3 * 0.0f;
    const float I2_11 = w2 * (zp_w1 - w7)   + w3 * 1.0f;
    const float I3_0  = zp_w4 + 0.0f * w5;
    const float I3_1  = zp_w4 + 1.0f * w5;
    const float I4_0  = 0.0f * w6;
    const float I4_1  = 1.0f * w6;
    const float I5_00 = w9 * (0.0f * w8) + w10 * 0.0f;
    const float I5_10 = w9 * (1.0f * w8) + w10 * 0.0f;
    const float I5_01 = w9 * (0.0f * w8) + w10 * 1.0f;
    const float I5_11 = w9 * (1.0f * w8) + w10 * 1.0f;
    const float I6_0  = 0.0f * w11;
    const float I6_1  = 1.0f * w11;

    const int lane = tid;                       // 0..13
    const int g = lane < 4 ? 0 : lane < 6 ? 1 : lane < 8 ? 2 : lane < 12 ? 3 : 4;
    const int g4 = g * 4;                       // nibble offset into pk

    // Per-lane parameters (ka = float(TAU*DT*a), computed in f64 like Python)
    const float ka = lane < 4 ? (float)(0.25 * 0.1) : (float)(0.25 * 0.02);
    const float b  = lane < 4 ? -0.075f
                   : (lane < 8 ? 0.25f : (lane < 12 ? 0.2f : 0.25f));
    const float c  = lane < 6 ? -55.0f : -65.0f;
    const float d  = (lane >= 4 && lane < 6) ? 0.05f : 6.0f;
    float v = lane < 4 ? -60.0f : (lane < 8 ? -64.0f : (lane < 12 ? -70.0f : -64.0f));
    float u = lane < 4 ? 4.5f   : (lane < 8 ? -16.0f : (lane < 12 ? -14.0f : -16.0f));

    const float I =
        lane == 0 ? I2_00 : lane == 1 ? I2_10 : lane == 2 ? I2_01 : lane == 3 ? I2_11 :
        lane == 4 ? I3_0  : lane == 5 ? I3_1  : lane == 6 ? I4_0  : lane == 7 ? I4_1  :
        lane == 8 ? I5_00 : lane == 9 ? I5_10 : lane == 10 ? I5_01 : lane == 11 ? I5_11 :
        lane == 12 ? I6_0 : I6_1;

    float* __restrict__ psp = out + g * T;           // spikes row base (per lane)
    float* __restrict__ pvv = out + 5 * T + g * T;   // volts row base (per lane)

    int z2p = 0, z4p = 0, z5p = 0;   // uniform scalars (sgpr)

    for (int t = 0; t < T; ++t) {
        // ---- one izh sequence updates all 14 speculative lanes ----
        float t1 = 0.04f * v;
        float t2 = t1 * v;
        float t3 = 5.0f * v;
        float t4 = t2 + t3;
        float t5 = t4 + 140.0f;
        float t6 = t5 - u;
        float t7 = t6 + I;
        float dv = 0.25f * t7;      // TAU*DT = 0.25 exactly
        float v1 = v + dv;
        float bv = b * v;
        float bvu = bv - u;
        float du = ka * bvu;
        float u1 = u + du;
        bool fire = (v1 >= 30.0f);
        unsigned long long m = __ballot(fire);
        float vr = fire ? c : v1;
        float ur = fire ? (u1 + d) : u1;   // z*d is exactly d or +0.0f

        // ---- scalar (uniform) spike resolution from the ballot mask ----
        int ln2 = z2p + 2 * z4p;                         // actual LLBN lane
        int z2 = (int)((m >> ln2) & 1ull);
        int z3 = (int)((m >> (4 + z2)) & 1ull);
        int z4 = (int)((m >> (6 + z3)) & 1ull);
        int tn = 8 + z3 + 2 * z5p;                       // actual TN lane
        int z5 = (int)((m >> tn) & 1ull);
        int z6 = (int)((m >> (12 + z5)) & 1ull);

        // packed actual-source-lane nibbles for all 5 groups
        int pk = ln2 | ((4 + z2) << 4) | ((6 + z3) << 8) | (tn << 12)
               | ((12 + z5) << 16);
        int zpk = z2 | (z3 << 1) | (z4 << 2) | (z5 << 3) | (z6 << 4);

        // ---- broadcast actual (v,u) back to every lane of each group ----
        int src = (pk >> g4) & 15;
        int idx = src << 2;   // bpermute takes byte index = lane*4
        v = __uint_as_float((unsigned)__builtin_amdgcn_ds_bpermute(
                idx, (int)__float_as_uint(vr)));
        u = __uint_as_float((unsigned)__builtin_amdgcn_ds_bpermute(
                idx, (int)__float_as_uint(ur)));

        // ---- outputs: group-duplicate lanes store same value/address ----
        float zv = (float)((zpk >> g) & 1);
        psp[t] = zv;
        pvv[t] = v;

        z2p = z2; z4p = z4; z5p = z5;
    }
}

extern "C" void kernel_launch(void* const* d_in, const int* in_sizes, int n_in,
                              void* d_out, int out_size, void* d_ws, size_t ws_size,
                              hipStream_t stream) {
    const float* mat = (const float*)d_in[0];
    const float* w   = (const float*)d_in[1];
    // out_size = 2 outputs * 5 neurons * T  -> T = out_size/10
    int T = out_size / 10;
    net_sim<<<1, 256, 0, stream>>>(mat, w, (float*)d_out, T);
}

// Round 4
// 1455.762 us; speedup vs baseline: 2.0010x; 1.2032x over previous
//
#include <hip/hip_runtime.h>

// Exact-order float32 arithmetic: numpy/jax evaluate left-to-right with no
// FMA contraction. hipcc defaults to -ffp-contract=fast, which would change
// rounding -> possible spike-time shift -> large voltage absmax error.
#pragma clang fp contract(off)

// 9-lane speculative Izhikevich network, no cross-lane data movement.
// Lane map (wave 0):
//   0   : LLBN (no speculation: I2 depends only on prev-step bits)
//   1,2 : EBN  speculating z2 = 0,1
//   3,4 : IFN  speculating z3 = 0,1
//   5,6 : TN   speculating z3 = 0,1   (known z5p folded into candidates)
//   7,8 : MN   speculating z5 = 0,1
// Every lane of a group holds the ACTUAL (v,u). Per step:
//   1. common izh head t1..t6 + u-path (I-independent)
//   2. ballot tail with per-lane speculative I -> __ballot -> scalar resolve
//      z2 -> z3 -> z4,z5 (short SALU chain)
//   3. actual tail recomputed LOCALLY with I_act selected by one cndmask
//      (no bpermute/LDS -> removes the ~130-cycle round trip of R3)
//   4. fire/reset from local compare of the actual v1; stores.
// All selected I values are constants from the validated R2/R3 set, and the
// op sequence matches the reference exactly -> bit-exact (absmax 0.0).

__global__ __launch_bounds__(256) void net_sim(const float* __restrict__ mat,
                                               const float* __restrict__ w,
                                               float* __restrict__ out,
                                               int T) {
    __shared__ double red[256];
    const int tid = threadIdx.x;

    // ---- z_plus = sum(input_mat * w0), f32 products accumulated in f64 ----
    const float w0 = w[0];
    double s = 0.0;
    for (int i = tid; i < 127 * 127; i += 256) {
        float p = mat[i] * w0;   // elementwise product rounded to f32 (as ref)
        s += (double)p;
    }
    red[tid] = s;
    __syncthreads();
    #pragma unroll
    for (int off = 128; off > 0; off >>= 1) {
        if (tid < off) red[tid] += red[tid + off];
        __syncthreads();
    }
    if (tid >= 9) return;   // 9 lanes of wave 0 continue; no more barriers

    const float z_plus = (float)red[0];

    const float w2 = w[2], w3 = w[3], w5 = w[5], w6 = w[6], w7 = w[7],
                w8 = w[8], w9 = w[9], w10 = w[10], w11 = w[11];
    const float zp_w1 = z_plus * w[1];
    const float zp_w4 = z_plus * w[4];

    // Validated constant-I set (R2/R3, absmax 0.0). z*w is exactly +0.0f or
    // w; x + (+0.0f) == x for the values involved.
    const float I2_00 = w2 * (zp_w1 - 0.0f) + w3 * 0.0f;
    const float I2_10 = w2 * (zp_w1 - 0.0f) + w3 * 1.0f;
    const float I2_01 = w2 * (zp_w1 - w7)   + w3 * 0.0f;
    const float I2_11 = w2 * (zp_w1 - w7)   + w3 * 1.0f;
    const float I3_0  = zp_w4 + 0.0f * w5;
    const float I3_1  = zp_w4 + 1.0f * w5;
    const float I4_0  = 0.0f * w6;
    const float I4_1  = 1.0f * w6;
    const float I5_00 = w9 * (0.0f * w8) + w10 * 0.0f;
    const float I5_10 = w9 * (1.0f * w8) + w10 * 0.0f;
    const float I5_01 = w9 * (0.0f * w8) + w10 * 1.0f;
    const float I5_11 = w9 * (1.0f * w8) + w10 * 1.0f;
    const float I6_0  = 0.0f * w11;
    const float I6_1  = 1.0f * w11;

    const int lane = tid;  // 0..8
    const int g = lane == 0 ? 0 : lane <= 2 ? 1 : lane <= 4 ? 2 : lane <= 6 ? 3 : 4;

    // per-lane params; ka = float(TAU*DT*a) computed in f64 like Python
    const float ka = lane == 0 ? (float)(0.25 * 0.1) : (float)(0.25 * 0.02);
    const float b  = lane == 0 ? -0.075f : (g == 3 ? 0.2f : 0.25f);
    const float c  = g <= 1 ? -55.0f : -65.0f;
    const float d  = g == 1 ? 0.05f : 6.0f;
    float v = g == 0 ? -60.0f : (g == 3 ? -70.0f : -64.0f);
    float u = g == 0 ? 4.5f   : (g == 3 ? -14.0f : -16.0f);

    // candidate-I vectors: variant0 / variant1 of each group, for z5p=0 (a)
    // and z5p=1 (b). Lane 0's slot is overwritten per step with I2(z2p,z4p).
    const float C0a = g == 0 ? I2_00 : g == 1 ? I3_0 : g == 2 ? I4_0
                    : g == 3 ? I5_00 : I6_0;
    const float C0b = g == 0 ? I2_00 : g == 1 ? I3_0 : g == 2 ? I4_0
                    : g == 3 ? I5_01 : I6_0;
    const float C1a = g == 1 ? I3_1 : g == 2 ? I4_1 : g == 3 ? I5_10
                    : g == 4 ? I6_1 : 0.0f;
    const float C1b = g == 1 ? I3_1 : g == 2 ? I4_1 : g == 3 ? I5_11
                    : g == 4 ? I6_1 : 0.0f;

    const bool is_lane0  = (lane == 0);
    const bool spec_var1 = (lane == 2) | (lane == 4) | (lane == 6) | (lane == 8);
    const unsigned lanebit = 1u << lane;

    float* __restrict__ psp = out + g * T;           // spikes row
    float* __restrict__ pvv = out + 5 * T + g * T;   // volts row

    int z2 = 0, z4 = 0, z5 = 0;   // prev-step bits (z2p, z4p, z5p) — uniform

    for (int t = 0; t < T; ++t) {
        // ---- candidate-I prep from prev-step bits (off critical path) ----
        float fI2 = z4 ? (z2 ? I2_11 : I2_01) : (z2 ? I2_10 : I2_00);
        float V0 = z5 ? C0b : C0a;
        float V1 = z5 ? C1b : C1a;
        V0 = is_lane0 ? fI2 : V0;
        float Ib = spec_var1 ? V1 : V0;   // this lane's ballot variant

        // ---- common izh head (I-independent) ----
        float t1 = 0.04f * v;
        float t2 = t1 * v;
        float t3 = 5.0f * v;
        float t4 = t2 + t3;
        float t5 = t4 + 140.0f;
        float t6 = t5 - u;
        float bv = b * v;
        float bvu = bv - u;
        float du = ka * bvu;
        float u1 = u + du;

        // ---- speculative (ballot) tail ----
        float t7b = t6 + Ib;
        float dvb = 0.25f * t7b;     // TAU*DT = 0.25 exactly
        float v1b = v + dvb;
        unsigned long long m = __ballot(v1b >= 30.0f);

        // ---- scalar resolution (uniform) ----
        int nz2 = (int)(m & 1ull);
        int z3  = (int)((m >> (1 + nz2)) & 1ull);
        int nz4 = (int)((m >> (3 + z3)) & 1ull);
        int nz5 = (int)((m >> (5 + z3)) & 1ull);
        unsigned ssel = (nz2 ? 0x006u : 0u) | (z3 ? 0x078u : 0u)
                      | (nz5 ? 0x180u : 0u);

        // ---- actual tail, recomputed locally (no cross-lane move) ----
        bool asel = (ssel & lanebit) != 0u;
        float Ia = asel ? V1 : V0;
        float t7a = t6 + Ia;
        float dva = 0.25f * t7a;
        float v1a = v + dva;
        bool fa = (v1a >= 30.0f);          // actual fire, local compare
        v = fa ? c : v1a;
        float u1d = u1 + d;
        u = fa ? u1d : u1;                 // z*d is exactly d or +0.0f

        // ---- outputs (group-duplicate lanes store same value/address) ----
        float zv = fa ? 1.0f : 0.0f;
        psp[t] = zv;
        pvv[t] = v;

        z2 = nz2; z4 = nz4; z5 = nz5;
    }
}

extern "C" void kernel_launch(void* const* d_in, const int* in_sizes, int n_in,
                              void* d_out, int out_size, void* d_ws, size_t ws_size,
                              hipStream_t stream) {
    const float* mat = (const float*)d_in[0];
    const float* w   = (const float*)d_in[1];
    // out_size = 2 outputs * 5 neurons * T  -> T = out_size/10
    int T = out_size / 10;
    net_sim<<<1, 256, 0, stream>>>(mat, w, (float*)d_out, T);
}

// Round 5
// 1210.856 us; speedup vs baseline: 2.4058x; 1.2023x over previous
//
#include <hip/hip_runtime.h>

// Exact-order float32 arithmetic: numpy/jax evaluate left-to-right with no
// FMA contraction. hipcc defaults to -ffp-contract=fast, which would change
// rounding -> possible spike-time shift -> large voltage absmax error.
#pragma clang fp contract(off)

// 9-lane speculative Izhikevich network (R4 datapath, bit-exact absmax 0.0)
// + 8-step store batching (R5).
// Lane map (wave 0):
//   0   : LLBN (no speculation: I2 depends only on prev-step bits)
//   1,2 : EBN  speculating z2 = 0,1
//   3,4 : IFN  speculating z3 = 0,1
//   5,6 : TN   speculating z3 = 0,1   (known z5p folded into candidates)
//   7,8 : MN   speculating z5 = 0,1
// Per step: common izh head -> speculative ballot tail -> scalar resolve of
// z2,z3,z4,z5 -> actual tail recomputed locally (I selected by cndmask).
// R5 change: z/v outputs are buffered in registers for 8 steps and flushed
// with float4 stores, so the per-step s_waitcnt on in-flight store registers
// (the R3/R4 bottleneck: ~250 cyc/step of store-latency serialization) is
// amortized 8x and overlapped with compute.

__global__ __launch_bounds__(256) void net_sim(const float* __restrict__ mat,
                                               const float* __restrict__ w,
                                               float* __restrict__ out,
                                               int T) {
    __shared__ double red[256];
    const int tid = threadIdx.x;

    // ---- z_plus = sum(input_mat * w0), f32 products accumulated in f64 ----
    const float w0 = w[0];
    double s = 0.0;
    for (int i = tid; i < 127 * 127; i += 256) {
        float p = mat[i] * w0;   // elementwise product rounded to f32 (as ref)
        s += (double)p;
    }
    red[tid] = s;
    __syncthreads();
    #pragma unroll
    for (int off = 128; off > 0; off >>= 1) {
        if (tid < off) red[tid] += red[tid + off];
        __syncthreads();
    }
    if (tid >= 9) return;   // 9 lanes of wave 0 continue; no more barriers

    const float z_plus = (float)red[0];

    const float w2 = w[2], w3 = w[3], w5 = w[5], w6 = w[6], w7 = w[7],
                w8 = w[8], w9 = w[9], w10 = w[10], w11 = w[11];
    const float zp_w1 = z_plus * w[1];
    const float zp_w4 = z_plus * w[4];

    // Validated constant-I set (R2/R3/R4, absmax 0.0). z*w is exactly +0.0f
    // or w; x + (+0.0f) == x for the values involved.
    const float I2_00 = w2 * (zp_w1 - 0.0f) + w3 * 0.0f;
    const float I2_10 = w2 * (zp_w1 - 0.0f) + w3 * 1.0f;
    const float I2_01 = w2 * (zp_w1 - w7)   + w3 * 0.0f;
    const float I2_11 = w2 * (zp_w1 - w7)   + w3 * 1.0f;
    const float I3_0  = zp_w4 + 0.0f * w5;
    const float I3_1  = zp_w4 + 1.0f * w5;
    const float I4_0  = 0.0f * w6;
    const float I4_1  = 1.0f * w6;
    const float I5_00 = w9 * (0.0f * w8) + w10 * 0.0f;
    const float I5_10 = w9 * (1.0f * w8) + w10 * 0.0f;
    const float I5_01 = w9 * (0.0f * w8) + w10 * 1.0f;
    const float I5_11 = w9 * (1.0f * w8) + w10 * 1.0f;
    const float I6_0  = 0.0f * w11;
    const float I6_1  = 1.0f * w11;

    const int lane = tid;  // 0..8
    const int g = lane == 0 ? 0 : lane <= 2 ? 1 : lane <= 4 ? 2 : lane <= 6 ? 3 : 4;

    // per-lane params; ka = float(TAU*DT*a) computed in f64 like Python
    const float ka = lane == 0 ? (float)(0.25 * 0.1) : (float)(0.25 * 0.02);
    const float b  = lane == 0 ? -0.075f : (g == 3 ? 0.2f : 0.25f);
    const float c  = g <= 1 ? -55.0f : -65.0f;
    const float d  = g == 1 ? 0.05f : 6.0f;
    float v = g == 0 ? -60.0f : (g == 3 ? -70.0f : -64.0f);
    float u = g == 0 ? 4.5f   : (g == 3 ? -14.0f : -16.0f);

    // candidate-I vectors: variant0/variant1 per group, for z5p=0(a)/1(b).
    const float C0a = g == 0 ? I2_00 : g == 1 ? I3_0 : g == 2 ? I4_0
                    : g == 3 ? I5_00 : I6_0;
    const float C0b = g == 0 ? I2_00 : g == 1 ? I3_0 : g == 2 ? I4_0
                    : g == 3 ? I5_01 : I6_0;
    const float C1a = g == 1 ? I3_1 : g == 2 ? I4_1 : g == 3 ? I5_10
                    : g == 4 ? I6_1 : 0.0f;
    const float C1b = g == 1 ? I3_1 : g == 2 ? I4_1 : g == 3 ? I5_11
                    : g == 4 ? I6_1 : 0.0f;

    const bool is_lane0  = (lane == 0);
    const bool spec_var1 = (lane == 2) | (lane == 4) | (lane == 6) | (lane == 8);
    const unsigned lanebit = 1u << lane;

    float* __restrict__ psp = out + g * T;           // spikes row
    float* __restrict__ pvv = out + 5 * T + g * T;   // volts row

    int z2 = 0, z4 = 0, z5 = 0;   // prev-step bits (z2p, z4p, z5p) — uniform

    float zb[8], vb[8];

    int t = 0;
    for (; t + 8 <= T; t += 8) {
        #pragma unroll
        for (int j = 0; j < 8; ++j) {
            // candidate-I prep from prev-step bits (off critical path)
            float fI2 = z4 ? (z2 ? I2_11 : I2_01) : (z2 ? I2_10 : I2_00);
            float V0 = z5 ? C0b : C0a;
            float V1 = z5 ? C1b : C1a;
            V0 = is_lane0 ? fI2 : V0;
            float Ib = spec_var1 ? V1 : V0;

            // common izh head (I-independent)
            float t1 = 0.04f * v;
            float t2 = t1 * v;
            float t3 = 5.0f * v;
            float t4 = t2 + t3;
            float t5 = t4 + 140.0f;
            float t6 = t5 - u;
            float bv = b * v;
            float bvu = bv - u;
            float du = ka * bvu;
            float u1 = u + du;

            // speculative (ballot) tail
            float t7b = t6 + Ib;
            float dvb = 0.25f * t7b;     // TAU*DT = 0.25 exactly
            float v1b = v + dvb;
            unsigned long long m = __ballot(v1b >= 30.0f);

            // scalar resolution (uniform)
            int nz2 = (int)(m & 1ull);
            int z3  = (int)((m >> (1 + nz2)) & 1ull);
            int nz4 = (int)((m >> (3 + z3)) & 1ull);
            int nz5 = (int)((m >> (5 + z3)) & 1ull);
            unsigned ssel = (nz2 ? 0x006u : 0u) | (z3 ? 0x078u : 0u)
                          | (nz5 ? 0x180u : 0u);

            // actual tail, recomputed locally
            bool asel = (ssel & lanebit) != 0u;
            float Ia = asel ? V1 : V0;
            float t7a = t6 + Ia;
            float dva = 0.25f * t7a;
            float v1a = v + dva;
            bool fa = (v1a >= 30.0f);
            v = fa ? c : v1a;
            float u1d = u1 + d;
            u = fa ? u1d : u1;           // z*d is exactly d or +0.0f

            zb[j] = fa ? 1.0f : 0.0f;
            vb[j] = v;

            z2 = nz2; z4 = nz4; z5 = nz5;
        }
        // batched flush: rows are 16B-aligned at t (t % 8 == 0, T % 8 == 0
        // for T=10000; general T handled by the tail loop)
        *(float4*)(psp)     = make_float4(zb[0], zb[1], zb[2], zb[3]);
        *(float4*)(psp + 4) = make_float4(zb[4], zb[5], zb[6], zb[7]);
        *(float4*)(pvv)     = make_float4(vb[0], vb[1], vb[2], vb[3]);
        *(float4*)(pvv + 4) = make_float4(vb[4], vb[5], vb[6], vb[7]);
        psp += 8;
        pvv += 8;
    }
    // tail (T not divisible by 8)
    for (; t < T; ++t) {
        float fI2 = z4 ? (z2 ? I2_11 : I2_01) : (z2 ? I2_10 : I2_00);
        float V0 = z5 ? C0b : C0a;
        float V1 = z5 ? C1b : C1a;
        V0 = is_lane0 ? fI2 : V0;
        float Ib = spec_var1 ? V1 : V0;
        float t1 = 0.04f * v;
        float t2 = t1 * v;
        float t3 = 5.0f * v;
        float t4 = t2 + t3;
        float t5 = t4 + 140.0f;
        float t6 = t5 - u;
        float bv = b * v;
        float bvu = bv - u;
        float du = ka * bvu;
        float u1 = u + du;
        float t7b = t6 + Ib;
        float dvb = 0.25f * t7b;
        float v1b = v + dvb;
        unsigned long long m = __ballot(v1b >= 30.0f);
        int nz2 = (int)(m & 1ull);
        int z3  = (int)((m >> (1 + nz2)) & 1ull);
        int nz4 = (int)((m >> (3 + z3)) & 1ull);
        int nz5 = (int)((m >> (5 + z3)) & 1ull);
        unsigned ssel = (nz2 ? 0x006u : 0u) | (z3 ? 0x078u : 0u)
                      | (nz5 ? 0x180u : 0u);
        bool asel = (ssel & lanebit) != 0u;
        float Ia = asel ? V1 : V0;
        float t7a = t6 + Ia;
        float dva = 0.25f * t7a;
        float v1a = v + dva;
        bool fa = (v1a >= 30.0f);
        v = fa ? c : v1a;
        float u1d = u1 + d;
        u = fa ? u1d : u1;
        psp[0] = fa ? 1.0f : 0.0f;
        pvv[0] = v;
        ++psp; ++pvv;
        z2 = nz2; z4 = nz4; z5 = nz5;
    }
}

extern "C" void kernel_launch(void* const* d_in, const int* in_sizes, int n_in,
                              void* d_out, int out_size, void* d_ws, size_t ws_size,
                              hipStream_t stream) {
    const float* mat = (const float*)d_in[0];
    const float* w   = (const float*)d_in[1];
    // out_size = 2 outputs * 5 neurons * T  -> T = out_size/10
    int T = out_size / 10;
    net_sim<<<1, 256, 0, stream>>>(mat, w, (float*)d_out, T);
}

// Round 6
// 346.055 us; speedup vs baseline: 8.4178x; 3.4990x over previous
//
#include <hip/hip_runtime.h>

// Exact-order float32 arithmetic: numpy/jax evaluate left-to-right with no
// FMA contraction. hipcc defaults to -ffp-contract=fast, which would change
// rounding -> possible spike-time shift -> large voltage absmax error.
#pragma clang fp contract(off)

// R5 datapath (9-lane speculative Izhikevich, bit-exact absmax 0.0)
// + R6: exact-cycle detection (Brent anchors at power-of-2 steps, bitwise
// state equality at 8-step block boundaries). The network state is
// (v,u) x 5 neurons + 3 carry bits; equal state ==> identical continuation,
// so the remaining output is a periodic copy of the detected window.
// Kernel fill_cycle performs that copy with a parallel grid.

__global__ __launch_bounds__(256) void net_sim(const float* __restrict__ mat,
                                               const float* __restrict__ w,
                                               float* __restrict__ out,
                                               int* __restrict__ ws,
                                               int T) {
    __shared__ double red[256];
    const int tid = threadIdx.x;

    // ---- z_plus = sum(input_mat * w0), f32 products accumulated in f64 ----
    const float w0 = w[0];
    double s = 0.0;
    for (int i = tid; i < 127 * 127; i += 256) {
        float p = mat[i] * w0;   // elementwise product rounded to f32 (as ref)
        s += (double)p;
    }
    red[tid] = s;
    __syncthreads();
    #pragma unroll
    for (int off = 128; off > 0; off >>= 1) {
        if (tid < off) red[tid] += red[tid + off];
        __syncthreads();
    }
    if (tid >= 9) return;   // 9 lanes of wave 0 continue; no more barriers

    const float z_plus = (float)red[0];

    const float w2 = w[2], w3 = w[3], w5 = w[5], w6 = w[6], w7 = w[7],
                w8 = w[8], w9 = w[9], w10 = w[10], w11 = w[11];
    const float zp_w1 = z_plus * w[1];
    const float zp_w4 = z_plus * w[4];

    // Validated constant-I set (R2..R5, absmax 0.0). z*w is exactly +0.0f
    // or w; x + (+0.0f) == x for the values involved.
    const float I2_00 = w2 * (zp_w1 - 0.0f) + w3 * 0.0f;
    const float I2_10 = w2 * (zp_w1 - 0.0f) + w3 * 1.0f;
    const float I2_01 = w2 * (zp_w1 - w7)   + w3 * 0.0f;
    const float I2_11 = w2 * (zp_w1 - w7)   + w3 * 1.0f;
    const float I3_0  = zp_w4 + 0.0f * w5;
    const float I3_1  = zp_w4 + 1.0f * w5;
    const float I4_0  = 0.0f * w6;
    const float I4_1  = 1.0f * w6;
    const float I5_00 = w9 * (0.0f * w8) + w10 * 0.0f;
    const float I5_10 = w9 * (1.0f * w8) + w10 * 0.0f;
    const float I5_01 = w9 * (0.0f * w8) + w10 * 1.0f;
    const float I5_11 = w9 * (1.0f * w8) + w10 * 1.0f;
    const float I6_0  = 0.0f * w11;
    const float I6_1  = 1.0f * w11;

    const int lane = tid;  // 0..8
    const int g = lane == 0 ? 0 : lane <= 2 ? 1 : lane <= 4 ? 2 : lane <= 6 ? 3 : 4;

    // per-lane params; ka = float(TAU*DT*a) computed in f64 like Python
    const float ka = lane == 0 ? (float)(0.25 * 0.1) : (float)(0.25 * 0.02);
    const float b  = lane == 0 ? -0.075f : (g == 3 ? 0.2f : 0.25f);
    const float c  = g <= 1 ? -55.0f : -65.0f;
    const float d  = g == 1 ? 0.05f : 6.0f;
    float v = g == 0 ? -60.0f : (g == 3 ? -70.0f : -64.0f);
    float u = g == 0 ? 4.5f   : (g == 3 ? -14.0f : -16.0f);

    // candidate-I vectors: variant0/variant1 per group, for z5p=0(a)/1(b).
    const float C0a = g == 0 ? I2_00 : g == 1 ? I3_0 : g == 2 ? I4_0
                    : g == 3 ? I5_00 : I6_0;
    const float C0b = g == 0 ? I2_00 : g == 1 ? I3_0 : g == 2 ? I4_0
                    : g == 3 ? I5_01 : I6_0;
    const float C1a = g == 1 ? I3_1 : g == 2 ? I4_1 : g == 3 ? I5_10
                    : g == 4 ? I6_1 : 0.0f;
    const float C1b = g == 1 ? I3_1 : g == 2 ? I4_1 : g == 3 ? I5_11
                    : g == 4 ? I6_1 : 0.0f;

    const bool is_lane0  = (lane == 0);
    const bool spec_var1 = (lane == 2) | (lane == 4) | (lane == 6) | (lane == 8);
    const unsigned lanebit = 1u << lane;

    float* __restrict__ psp = out + g * T;           // spikes row
    float* __restrict__ pvv = out + 5 * T + g * T;   // volts row

    int z2 = 0, z4 = 0, z5 = 0;   // prev-step bits (z2p, z4p, z5p) — uniform

    // ---- cycle-detection state (Brent: anchors at powers of two) ----
    float av = 0.0f, au = 0.0f;
    int az2 = 0, az4 = 0, az5 = 0;
    int anchor_t = -1, next_anchor = 8;
    int t_det = -1, Pf = 0;

    float zb[8], vb[8];

    int t = 0;
    for (; t + 8 <= T; t += 8) {
        // ---- block-top: anchor capture / exact-state cycle check ----
        if (t == next_anchor) {
            av = v; au = u; az2 = z2; az4 = z4; az5 = z5;
            anchor_t = t; next_anchor <<= 1;
        } else if (anchor_t >= 0) {
            unsigned long long mv =
                __ballot(__float_as_uint(v) == __float_as_uint(av));
            unsigned long long mu =
                __ballot(__float_as_uint(u) == __float_as_uint(au));
            if (((mv & mu) & 0x1FFull) == 0x1FFull &&
                z2 == az2 && z4 == az4 && z5 == az5) {
                // state entering step t bit-equals state entering anchor_t:
                // outputs from t onward repeat window [anchor_t, t).
                t_det = t; Pf = t - anchor_t;
                break;
            }
        }

        #pragma unroll
        for (int j = 0; j < 8; ++j) {
            // candidate-I prep from prev-step bits (off critical path)
            float fI2 = z4 ? (z2 ? I2_11 : I2_01) : (z2 ? I2_10 : I2_00);
            float V0 = z5 ? C0b : C0a;
            float V1 = z5 ? C1b : C1a;
            V0 = is_lane0 ? fI2 : V0;
            float Ib = spec_var1 ? V1 : V0;

            // common izh head (I-independent)
            float t1 = 0.04f * v;
            float t2 = t1 * v;
            float t3 = 5.0f * v;
            float t4 = t2 + t3;
            float t5 = t4 + 140.0f;
            float t6 = t5 - u;
            float bv = b * v;
            float bvu = bv - u;
            float du = ka * bvu;
            float u1 = u + du;

            // speculative (ballot) tail
            float t7b = t6 + Ib;
            float dvb = 0.25f * t7b;     // TAU*DT = 0.25 exactly
            float v1b = v + dvb;
            unsigned long long m = __ballot(v1b >= 30.0f);

            // scalar resolution (uniform)
            int nz2 = (int)(m & 1ull);
            int z3  = (int)((m >> (1 + nz2)) & 1ull);
            int nz4 = (int)((m >> (3 + z3)) & 1ull);
            int nz5 = (int)((m >> (5 + z3)) & 1ull);
            unsigned ssel = (nz2 ? 0x006u : 0u) | (z3 ? 0x078u : 0u)
                          | (nz5 ? 0x180u : 0u);

            // actual tail, recomputed locally
            bool asel = (ssel & lanebit) != 0u;
            float Ia = asel ? V1 : V0;
            float t7a = t6 + Ia;
            float dva = 0.25f * t7a;
            float v1a = v + dva;
            bool fa = (v1a >= 30.0f);
            v = fa ? c : v1a;
            float u1d = u1 + d;
            u = fa ? u1d : u1;           // z*d is exactly d or +0.0f

            zb[j] = fa ? 1.0f : 0.0f;
            vb[j] = v;

            z2 = nz2; z4 = nz4; z5 = nz5;
        }
        // batched flush (rows 16B-aligned at t; t % 8 == 0)
        *(float4*)(psp)     = make_float4(zb[0], zb[1], zb[2], zb[3]);
        *(float4*)(psp + 4) = make_float4(zb[4], zb[5], zb[6], zb[7]);
        *(float4*)(pvv)     = make_float4(vb[0], vb[1], vb[2], vb[3]);
        *(float4*)(pvv + 4) = make_float4(vb[4], vb[5], vb[6], vb[7]);
        psp += 8;
        pvv += 8;
    }
    // tail (T not divisible by 8), only when no cycle was detected
    for (; t < T && t_det < 0; ++t) {
        float fI2 = z4 ? (z2 ? I2_11 : I2_01) : (z2 ? I2_10 : I2_00);
        float V0 = z5 ? C0b : C0a;
        float V1 = z5 ? C1b : C1a;
        V0 = is_lane0 ? fI2 : V0;
        float Ib = spec_var1 ? V1 : V0;
        float t1 = 0.04f * v;
        float t2 = t1 * v;
        float t3 = 5.0f * v;
        float t4 = t2 + t3;
        float t5 = t4 + 140.0f;
        float t6 = t5 - u;
        float bv = b * v;
        float bvu = bv - u;
        float du = ka * bvu;
        float u1 = u + du;
        float t7b = t6 + Ib;
        float dvb = 0.25f * t7b;
        float v1b = v + dvb;
        unsigned long long m = __ballot(v1b >= 30.0f);
        int nz2 = (int)(m & 1ull);
        int z3  = (int)((m >> (1 + nz2)) & 1ull);
        int nz4 = (int)((m >> (3 + z3)) & 1ull);
        int nz5 = (int)((m >> (5 + z3)) & 1ull);
        unsigned ssel = (nz2 ? 0x006u : 0u) | (z3 ? 0x078u : 0u)
                      | (nz5 ? 0x180u : 0u);
        bool asel = (ssel & lanebit) != 0u;
        float Ia = asel ? V1 : V0;
        float t7a = t6 + Ia;
        float dva = 0.25f * t7a;
        float v1a = v + dva;
        bool fa = (v1a >= 30.0f);
        v = fa ? c : v1a;
        float u1d = u1 + d;
        u = fa ? u1d : u1;
        psp[0] = fa ? 1.0f : 0.0f;
        pvv[0] = v;
        ++psp; ++pvv;
        z2 = nz2; z4 = nz4; z5 = nz5;
    }

    // publish detection result (ws is re-poisoned before every call)
    if (lane == 0) {
        ws[0] = (t_det >= 0) ? 1 : 0;
        ws[1] = t_det;
        ws[2] = Pf;
    }
}

// Fills out[r, t] for t in [t_det, T) with the periodic continuation
// out[r, t_det - P + ((t - t_det) mod P)]. No-op when no cycle was found.
__global__ __launch_bounds__(256) void fill_cycle(float* __restrict__ out,
                                                  const int* __restrict__ ws,
                                                  int T) {
    if (ws[0] == 0) return;
    const int t0 = ws[1];
    const int P  = ws[2];
    const int r  = blockIdx.y;                    // 0..9 (row)
    const float* __restrict__ src = out + (size_t)r * T + (t0 - P);
    float* __restrict__ dst       = out + (size_t)r * T + t0;
    const int n = T - t0;
    for (int i = blockIdx.x * blockDim.x + threadIdx.x; i < n;
         i += gridDim.x * blockDim.x) {
        dst[i] = src[i % P];
    }
}

extern "C" void kernel_launch(void* const* d_in, const int* in_sizes, int n_in,
                              void* d_out, int out_size, void* d_ws, size_t ws_size,
                              hipStream_t stream) {
    const float* mat = (const float*)d_in[0];
    const float* w   = (const float*)d_in[1];
    // out_size = 2 outputs * 5 neurons * T  -> T = out_size/10
    int T = out_size / 10;
    net_sim<<<1, 256, 0, stream>>>(mat, w, (float*)d_out, (int*)d_ws, T);
    dim3 grid(40, 10, 1);
    fill_cycle<<<grid, 256, 0, stream>>>((float*)d_out, (const int*)d_ws, T);
}

// Round 7
// 328.441 us; speedup vs baseline: 8.8692x; 1.0536x over previous
//
#include <hip/hip_runtime.h>

// Exact-order float32 arithmetic: numpy/jax evaluate left-to-right with no
// FMA contraction. hipcc defaults to -ffp-contract=fast, which would change
// rounding -> possible spike-time shift -> large voltage absmax error.
#pragma clang fp contract(off)

// R7: 5-lane dual-variant speculative Izhikevich network + fine-cadence
// exact-cycle detection.
//   lane g: neuron g (0 LLBN, 1 EBN, 2 IFN, 3 TN, 4 MN). Each lane computes
//   BOTH speculative v1 variants locally (variant = the one unknown input
//   bit; LLBN has none - its I is fully determined by prev-step bits).
//   Two ballots (variant0-fire, variant1-fire) -> scalar resolve of the
//   actual bit chain z2 -> z3 -> z4,z5 -> z6 -> lane-mask built in SGPRs ->
//   v_cndmask_b32 with the mask directly as ssrc2 (no per-lane cond prep).
// Cycle detection: state = {v,u} x 5 lanes + carry bits (z2p,z4p,z5p).
// Bitwise state equality to an anchor => outputs repeat the window
// [anchor, t). Fine anchors every 64 steps catch the period (P=40 observed
// in R6) right after the transient ends; power-of-2 (Brent) anchors are the
// fallback for any period > 56. fill_cycle copies the periodic continuation.

__device__ __forceinline__ float sel_mask(float a, float b, unsigned long long m) {
    float r;
    // D = m.bit[lane] ? S1 : S0   (VOP3 v_cndmask with SGPR-pair condition)
    asm("v_cndmask_b32 %0, %1, %2, %3" : "=v"(r) : "v"(a), "v"(b), "s"(m));
    return r;
}

__global__ __launch_bounds__(256) void net_sim(const float* __restrict__ mat,
                                               const float* __restrict__ w,
                                               float* __restrict__ out,
                                               int* __restrict__ ws,
                                               int T) {
    __shared__ double red[256];
    const int tid = threadIdx.x;

    // ---- z_plus = sum(input_mat * w0), f32 products accumulated in f64 ----
    const float w0 = w[0];
    double s = 0.0;
    for (int i = tid; i < 127 * 127; i += 256) {
        float p = mat[i] * w0;   // elementwise product rounded to f32 (as ref)
        s += (double)p;
    }
    red[tid] = s;
    __syncthreads();
    #pragma unroll
    for (int off = 128; off > 0; off >>= 1) {
        if (tid < off) red[tid] += red[tid + off];
        __syncthreads();
    }
    if (tid >= 5) return;   // 5 lanes of wave 0 continue; no more barriers

    const float z_plus = (float)red[0];

    const float w2 = w[2], w3 = w[3], w5 = w[5], w6 = w[6], w7 = w[7],
                w8 = w[8], w9 = w[9], w10 = w[10], w11 = w[11];
    const float zp_w1 = z_plus * w[1];
    const float zp_w4 = z_plus * w[4];

    // Validated constant-I set (R2..R6, absmax 0.0). z*w is exactly +0.0f
    // or w; x + (+0.0f) == x for the values involved.
    const float I2_00 = w2 * (zp_w1 - 0.0f) + w3 * 0.0f;
    const float I2_10 = w2 * (zp_w1 - 0.0f) + w3 * 1.0f;
    const float I2_01 = w2 * (zp_w1 - w7)   + w3 * 0.0f;
    const float I2_11 = w2 * (zp_w1 - w7)   + w3 * 1.0f;
    const float I3_0  = zp_w4 + 0.0f * w5;
    const float I3_1  = zp_w4 + 1.0f * w5;
    const float I4_0  = 0.0f * w6;
    const float I4_1  = 1.0f * w6;
    const float I5_00 = w9 * (0.0f * w8) + w10 * 0.0f;   // (z3, z5p)
    const float I5_10 = w9 * (1.0f * w8) + w10 * 0.0f;
    const float I5_01 = w9 * (0.0f * w8) + w10 * 1.0f;
    const float I5_11 = w9 * (1.0f * w8) + w10 * 1.0f;
    const float I6_0  = 0.0f * w11;
    const float I6_1  = 1.0f * w11;

    const int lane = tid;  // 0..4 == neuron index
    // per-lane params; ka = float(TAU*DT*a) computed in f64 like Python
    const float ka = lane == 0 ? (float)(0.25 * 0.1) : (float)(0.25 * 0.02);
    const float b  = lane == 0 ? -0.075f : (lane == 3 ? 0.2f : 0.25f);
    const float cc = lane <= 1 ? -55.0f : -65.0f;
    const float d  = lane == 1 ? 0.05f : 6.0f;
    float v = lane == 0 ? -60.0f : (lane == 3 ? -70.0f : -64.0f);
    float u = lane == 0 ? 4.5f   : (lane == 3 ? -14.0f : -16.0f);

    // per-lane variant-I constants, for z5p=0 (a) and z5p=1 (b); lane 0's
    // slots are overwritten each step with the fully-determined I2.
    const float K0a = lane == 1 ? I3_0 : lane == 2 ? I4_0 : lane == 3 ? I5_00
                    : lane == 4 ? I6_0 : 0.0f;
    const float K0b = lane == 3 ? I5_01 : K0a;
    const float K1a = lane == 1 ? I3_1 : lane == 2 ? I4_1 : lane == 3 ? I5_10
                    : lane == 4 ? I6_1 : 0.0f;
    const float K1b = lane == 3 ? I5_11 : K1a;
    const bool is_l0 = (lane == 0);

    float* __restrict__ psp = out + lane * T;           // spikes row
    float* __restrict__ pvv = out + 5 * T + lane * T;   // volts row

    int z2 = 0, z4 = 0, z5 = 0;   // prev-step bits (uniform, SGPR)

    // ---- cycle-detection state: fine anchors (every 64) + Brent fallback --
    float fav = 0.0f, fau = 0.0f; int faz2 = 0, faz4 = 0, faz5 = 0, fa_t = -1;
    float cav = 0.0f, cau = 0.0f; int caz2 = 0, caz4 = 0, caz5 = 0, ca_t = -1;
    int next_coarse = 8;
    int t_det = -1, Pf = 0;

    float zb[8], vb[8];

    int t = 0;
    for (; t + 8 <= T; t += 8) {
        // ---- block top: compare against anchors FIRST, then refresh ----
        int hitA = -1;
        if (fa_t >= 0) {
            unsigned long long mv =
                __ballot(__float_as_uint(v) == __float_as_uint(fav));
            unsigned long long mu =
                __ballot(__float_as_uint(u) == __float_as_uint(fau));
            if (((mv & mu) & 0x1Full) == 0x1Full &&
                z2 == faz2 && z4 == faz4 && z5 == faz5) hitA = fa_t;
        }
        if (hitA < 0 && ca_t >= 0) {
            unsigned long long mv =
                __ballot(__float_as_uint(v) == __float_as_uint(cav));
            unsigned long long mu =
                __ballot(__float_as_uint(u) == __float_as_uint(cau));
            if (((mv & mu) & 0x1Full) == 0x1Full &&
                z2 == caz2 && z4 == caz4 && z5 == caz5) hitA = ca_t;
        }
        if (hitA >= 0) { t_det = t; Pf = t - hitA; break; }
        if ((t & 63) == 0 && t) {
            fav = v; fau = u; faz2 = z2; faz4 = z4; faz5 = z5; fa_t = t;
        }
        if (t == next_coarse) {
            cav = v; cau = u; caz2 = z2; caz4 = z4; caz5 = z5; ca_t = t;
            next_coarse <<= 1;
        }

        #pragma unroll
        for (int j = 0; j < 8; ++j) {
            // per-step variant-I prep (off critical path)
            float fI2 = z4 ? (z2 ? I2_11 : I2_01) : (z2 ? I2_10 : I2_00);
            float J0 = z5 ? K0b : K0a;
            float J1 = z5 ? K1b : K1a;
            J0 = is_l0 ? fI2 : J0;
            J1 = is_l0 ? fI2 : J1;

            // common izh head (I-independent)
            float t1 = 0.04f * v;
            float t2 = t1 * v;
            float t3 = 5.0f * v;
            float t4 = t2 + t3;
            float t5 = t4 + 140.0f;
            float t6 = t5 - u;
            float bv = b * v;
            float bvu = bv - u;
            float du = ka * bvu;
            float u1 = u + du;
            float u1d = u1 + d;

            // both speculative tails (parallel, not serial)
            float t7_0 = t6 + J0;
            float dv_0 = 0.25f * t7_0;   // TAU*DT = 0.25 exactly
            float v1_0 = v + dv_0;
            float t7_1 = t6 + J1;
            float dv_1 = 0.25f * t7_1;
            float v1_1 = v + dv_1;
            unsigned long long m0 = __ballot(v1_0 >= 30.0f);
            unsigned long long m1 = __ballot(v1_1 >= 30.0f);

            // scalar resolution of the actual bit chain (uniform, SALU)
            int nz2 = (int)(m0 & 1ull);                       // LLBN: J0==J1
            unsigned long long me = nz2 ? m1 : m0;
            int z3  = (int)((me >> 1) & 1ull);                // EBN actual
            unsigned long long mi = z3 ? m1 : m0;
            int nz4 = (int)((mi >> 2) & 1ull);                // IFN actual
            int nz5 = (int)((mi >> 3) & 1ull);                // TN actual
            unsigned long long mm = nz5 ? m1 : m0;
            int nz6 = (int)((mm >> 4) & 1ull);                // MN actual

            // lane masks: which variant is actual / which neurons fired
            unsigned long long act = (nz2 ? 0x02ull : 0ull) |
                                     (z3  ? 0x0Cull : 0ull) |
                                     (nz5 ? 0x10ull : 0ull);
            unsigned long long fam = (unsigned long long)(nz2 | (z3 << 1) |
                                     (nz4 << 2) | (nz5 << 3) | (nz6 << 4));

            // final selects: mask used directly as cndmask ssrc2
            float v1a = sel_mask(v1_0, v1_1, act);
            v = sel_mask(v1a, cc, fam);
            u = sel_mask(u1, u1d, fam);    // z*d is exactly d or +0.0f
            zb[j] = sel_mask(0.0f, 1.0f, fam);
            vb[j] = v;

            z2 = nz2; z4 = nz4; z5 = nz5;
        }
        // batched flush (rows 16B-aligned at t; t % 8 == 0)
        *(float4*)(psp)     = make_float4(zb[0], zb[1], zb[2], zb[3]);
        *(float4*)(psp + 4) = make_float4(zb[4], zb[5], zb[6], zb[7]);
        *(float4*)(pvv)     = make_float4(vb[0], vb[1], vb[2], vb[3]);
        *(float4*)(pvv + 4) = make_float4(vb[4], vb[5], vb[6], vb[7]);
        psp += 8;
        pvv += 8;
    }
    // tail (T not divisible by 8), only when no cycle was detected
    for (; t < T && t_det < 0; ++t) {
        float fI2 = z4 ? (z2 ? I2_11 : I2_01) : (z2 ? I2_10 : I2_00);
        float J0 = z5 ? K0b : K0a;
        float J1 = z5 ? K1b : K1a;
        J0 = is_l0 ? fI2 : J0;
        J1 = is_l0 ? fI2 : J1;
        float t1 = 0.04f * v;
        float t2 = t1 * v;
        float t3 = 5.0f * v;
        float t4 = t2 + t3;
        float t5 = t4 + 140.0f;
        float t6 = t5 - u;
        float bv = b * v;
        float bvu = bv - u;
        float du = ka * bvu;
        float u1 = u + du;
        float u1d = u1 + d;
        float t7_0 = t6 + J0;
        float dv_0 = 0.25f * t7_0;
        float v1_0 = v + dv_0;
        float t7_1 = t6 + J1;
        float dv_1 = 0.25f * t7_1;
        float v1_1 = v + dv_1;
        unsigned long long m0 = __ballot(v1_0 >= 30.0f);
        unsigned long long m1 = __ballot(v1_1 >= 30.0f);
        int nz2 = (int)(m0 & 1ull);
        unsigned long long me = nz2 ? m1 : m0;
        int z3  = (int)((me >> 1) & 1ull);
        unsigned long long mi = z3 ? m1 : m0;
        int nz4 = (int)((mi >> 2) & 1ull);
        int nz5 = (int)((mi >> 3) & 1ull);
        unsigned long long mm = nz5 ? m1 : m0;
        int nz6 = (int)((mm >> 4) & 1ull);
        unsigned long long act = (nz2 ? 0x02ull : 0ull) |
                                 (z3  ? 0x0Cull : 0ull) |
                                 (nz5 ? 0x10ull : 0ull);
        unsigned long long fam = (unsigned long long)(nz2 | (z3 << 1) |
                                 (nz4 << 2) | (nz5 << 3) | (nz6 << 4));
        float v1a = sel_mask(v1_0, v1_1, act);
        v = sel_mask(v1a, cc, fam);
        u = sel_mask(u1, u1d, fam);
        psp[0] = sel_mask(0.0f, 1.0f, fam);
        pvv[0] = v;
        ++psp; ++pvv;
        z2 = nz2; z4 = nz4; z5 = nz5;
    }

    // publish detection result (ws is re-poisoned before every call)
    if (lane == 0) {
        ws[0] = (t_det >= 0) ? 1 : 0;
        ws[1] = t_det;
        ws[2] = Pf;
    }
}

// Fills out[r, t] for t in [t_det, T) with the periodic continuation
// out[r, t_det - P + ((t - t_det) mod P)]. No-op when no cycle was found.
__global__ __launch_bounds__(256) void fill_cycle(float* __restrict__ out,
                                                  const int* __restrict__ ws,
                                                  int T) {
    if (ws[0] == 0) return;
    const int t0 = ws[1];
    const int P  = ws[2];
    const int r  = blockIdx.y;                    // 0..9 (row)
    const float* __restrict__ src = out + (size_t)r * T + (t0 - P);
    float* __restrict__ dst       = out + (size_t)r * T + t0;
    const int n = T - t0;
    for (int i = blockIdx.x * blockDim.x + threadIdx.x; i < n;
         i += gridDim.x * blockDim.x) {
        dst[i] = src[i % P];
    }
}

extern "C" void kernel_launch(void* const* d_in, const int* in_sizes, int n_in,
                              void* d_out, int out_size, void* d_ws, size_t ws_size,
                              hipStream_t stream) {
    const float* mat = (const float*)d_in[0];
    const float* w   = (const float*)d_in[1];
    // out_size = 2 outputs * 5 neurons * T  -> T = out_size/10
    int T = out_size / 10;
    net_sim<<<1, 256, 0, stream>>>(mat, w, (float*)d_out, (int*)d_ws, T);
    dim3 grid(40, 10, 1);
    fill_cycle<<<grid, 256, 0, stream>>>((float*)d_out, (const int*)d_ws, T);
}